// Round 7
// baseline (108.368 us; speedup 1.0000x reference)
//
#include <hip/hip_runtime.h>

#define HWOUT 50176   // 224*224
#define NBLK  256     // stage1 grid; partial[] rows
#define CHUNK 1024    // rows per block-iteration (1024 threads, 1 row/thread)
#define NWAVE 16
#define REPS1 6       // instrumentation: stage1 repeats (idempotent)
#define REPS2 16      // instrumentation: out2 repeats (idempotent)

typedef __attribute__((ext_vector_type(8))) short short8;
typedef __attribute__((ext_vector_type(4))) float f32x4;

__device__ __forceinline__ float fast_sigmoid(float x) {
    float t = __builtin_amdgcn_exp2f(-1.44269504088896340736f * x);
    return __builtin_amdgcn_rcpf(1.0f + t);
}
__device__ __forceinline__ float silu_f(float x) { return x * fast_sigmoid(x); }

__device__ __forceinline__ short to_bf16_bits(float f) {
    unsigned u = __builtin_bit_cast(unsigned, f);
    u += 0x7FFFu + ((u >> 16) & 1u);   // round-to-nearest-even
    return (short)(u >> 16);
}

// ---------------- Stage 1 (R6 body, wrapped in reps loop)
__global__ __launch_bounds__(1024) void k_stage1(const float* __restrict__ x,
                                                 const float* __restrict__ W1,
                                                 const float* __restrict__ b1,
                                                 float* __restrict__ partial,
                                                 int N, int reps) {
    __shared__ short xs[CHUNK * 8];     // 16 KB bf16 rows (7 padded to 8)
    __shared__ float red[NWAVE][64];    // 4 KB
    const int t = threadIdx.x;
    const int lane = t & 63;
    const int wave = t >> 6;

    // B fragments: bf[g][j] = W1pad[8*(lane>>4)+j][g*16+(lane&15)], k>=7 -> 0
    const int krow = (lane >> 4) * 8;
    const int c = lane & 15;
    short8 bf[4];
    f32x4 biasC[4];
#pragma unroll
    for (int g = 0; g < 4; ++g) {
#pragma unroll
        for (int j = 0; j < 8; ++j) {
            int k = krow + j;
            float v = (k < 7) ? W1[k * 64 + g * 16 + c] : 0.0f;
            bf[g][j] = to_bf16_bits(v);
        }
        float bb = b1[g * 16 + c];
        biasC[g] = (f32x4){bb, bb, bb, bb};
    }

    const int nchunk = (N + CHUNK - 1) / CHUNK;
    const short8 zero8 = {0, 0, 0, 0, 0, 0, 0, 0};
    const f32x4 onev = {1.0f, 1.0f, 1.0f, 1.0f};
    const f32x4 nlog2e = {-1.44269504088896f, -1.44269504088896f,
                          -1.44269504088896f, -1.44269504088896f};

    for (int rep = 0; rep < reps; ++rep) {
        asm volatile("" ::: "memory");   // block cross-rep hoisting

        f32x4 accv[4];
#pragma unroll
        for (int g = 0; g < 4; ++g) accv[g] = (f32x4){0.0f, 0.0f, 0.0f, 0.0f};

        bool did_last = false;
        for (int ch = blockIdx.x; ch < nchunk; ch += NBLK) {
            did_last |= (ch == nchunk - 1);
            const int row = ch * CHUNK + t;
            __syncthreads();             // prior tile reads done before overwrite
            {
                float v[7];
                if (row < N) {
#pragma unroll
                    for (int k = 0; k < 7; ++k) v[k] = x[(size_t)row * 7 + k];
                } else {
#pragma unroll
                    for (int k = 0; k < 7; ++k) v[k] = 0.0f;   // phantom row
                }
                short8 p;
#pragma unroll
                for (int k = 0; k < 7; ++k) p[k] = to_bf16_bits(silu_f(v[k]));
                p[7] = 0;
                *reinterpret_cast<short8*>(&xs[t * 8]) = p;
            }
            __syncthreads();

#pragma unroll
            for (int tt = 0; tt < 4; ++tt) {
                const int tile = wave * 4 + tt;
                short8 av = *reinterpret_cast<short8*>(&xs[(tile * 16 + c) * 8]);
                av = (lane < 16) ? av : zero8;      // lanes>=16 are K-pad
#pragma unroll
                for (int g = 0; g < 4; ++g) {
                    f32x4 d = __builtin_amdgcn_mfma_f32_16x16x32_bf16(av, bf[g], biasC[g], 0, 0, 0);
                    f32x4 targ = d * nlog2e;
                    f32x4 ex;
                    ex[0] = __builtin_amdgcn_exp2f(targ[0]);
                    ex[1] = __builtin_amdgcn_exp2f(targ[1]);
                    ex[2] = __builtin_amdgcn_exp2f(targ[2]);
                    ex[3] = __builtin_amdgcn_exp2f(targ[3]);
                    f32x4 den = ex + onev;
                    f32x4 r;
                    r[0] = __builtin_amdgcn_rcpf(den[0]);
                    r[1] = __builtin_amdgcn_rcpf(den[1]);
                    r[2] = __builtin_amdgcn_rcpf(den[2]);
                    r[3] = __builtin_amdgcn_rcpf(den[3]);
                    accv[g] = d * r + accv[g];      // packed fma
                }
            }
        }

        float accf[4];
#pragma unroll
        for (int g = 0; g < 4; ++g) {
            accf[g] = (accv[g][0] + accv[g][1]) + (accv[g][2] + accv[g][3]);
            accf[g] += __shfl_xor(accf[g], 16, 64);
            accf[g] += __shfl_xor(accf[g], 32, 64);
        }
        __syncthreads();
        if (lane < 16) {
#pragma unroll
            for (int g = 0; g < 4; ++g) red[wave][g * 16 + lane] = accf[g];
        }
        __syncthreads();
        if (t < 64) {
            float s = 0.0f;
#pragma unroll
            for (int wv = 0; wv < NWAVE; ++wv) s += red[wv][t];
            if (did_last) {
                const int phantom = nchunk * CHUNK - N;
                s -= (float)phantom * silu_f(b1[t]);
            }
            partial[blockIdx.x * 64 + t] = s;
        }
        __syncthreads();                 // red[] safe next rep
    }
}

// ---------------- Stage 2 (R6 body, wrapped in reps loop)
__global__ __launch_bounds__(256) void k_out2(const float* __restrict__ partial,
                                              const float* __restrict__ W2,
                                              const float* __restrict__ b2,
                                              float* __restrict__ out,
                                              float invN, int reps) {
    __shared__ float4 red[256];
    __shared__ float ml[64];
    const int t = threadIdx.x;
    const int c4 = t & 15;
    const int grp = t >> 4;
    const float4* p4 = reinterpret_cast<const float4*>(partial);

    for (int rep = 0; rep < reps; ++rep) {
        asm volatile("" ::: "memory");   // block cross-rep hoisting

        float4 s = {0.0f, 0.0f, 0.0f, 0.0f};
#pragma unroll
        for (int r = grp; r < NBLK; r += 16) {
            float4 v = p4[r * 16 + c4];
            s.x += v.x; s.y += v.y; s.z += v.z; s.w += v.w;
        }
        red[t] = s;
        __syncthreads();
        if (t < 16) {
            float4 a = {0.0f, 0.0f, 0.0f, 0.0f};
#pragma unroll
            for (int g = 0; g < 16; ++g) {
                float4 v = red[g * 16 + t];
                a.x += v.x; a.y += v.y; a.z += v.z; a.w += v.w;
            }
            ml[4 * t + 0] = a.x * invN;
            ml[4 * t + 1] = a.y * invN;
            ml[4 * t + 2] = a.z * invN;
            ml[4 * t + 3] = a.w * invN;
        }
        __syncthreads();

        const int j = blockIdx.x * 256 + t;
        float acc[8];
#pragma unroll
        for (int i = 0; i < 8; ++i) acc[i] = 0.0f;
#pragma unroll
        for (int k8 = 0; k8 < 8; ++k8) {
#pragma unroll
            for (int i = 0; i < 8; ++i) {
                const int k = k8 * 8 + i;
                acc[i] = fmaf(ml[k], W2[(size_t)k * HWOUT + j], acc[i]);
            }
        }
        float a01 = acc[0] + acc[1], a23 = acc[2] + acc[3];
        float a45 = acc[4] + acc[5], a67 = acc[6] + acc[7];
        float e = ((a01 + a23) + (a45 + a67)) + b2[j];
        e = silu_f(e);
        out[j] = fminf(fmaxf(e, 0.0f), 1.0f);
        __syncthreads();                 // red[]/ml[] reuse safe next rep
    }
}

extern "C" void kernel_launch(void* const* d_in, const int* in_sizes, int n_in,
                              void* d_out, int out_size, void* d_ws, size_t ws_size,
                              hipStream_t stream) {
    const float* x  = (const float*)d_in[0];
    const float* W1 = (const float*)d_in[1];
    const float* b1 = (const float*)d_in[2];
    const float* W2 = (const float*)d_in[3];
    const float* b2 = (const float*)d_in[4];
    float* out = (float*)d_out;

    const int N = in_sizes[0] / 7;
    float* partial = (float*)d_ws;   // NBLK*64 floats = 64 KB

    k_stage1<<<NBLK, 1024, 0, stream>>>(x, W1, b1, partial, N, REPS1);
    k_out2<<<HWOUT / 256, 256, 0, stream>>>(partial, W2, b2, out, 1.0f / (float)N, REPS2);
}

// Round 8
// 22.794 us; speedup vs baseline: 4.7542x; 4.7542x over previous
//
#include <hip/hip_runtime.h>

#define HWOUT 50176   // 224*224
#define NBLK1 512     // stage1 grid: 2 blocks/CU -> 32 waves/CU co-resident
#define CHUNK 1024    // rows per block-iteration (1024 threads, 1 row/thread)
#define NWAVE 16
#define GRID2 196     // k_out2 grid: HWOUT / 256 outputs per block

typedef __attribute__((ext_vector_type(8))) short short8;
typedef __attribute__((ext_vector_type(4))) float f32x4;

__device__ __forceinline__ float fast_sigmoid(float x) {
    float t = __builtin_amdgcn_exp2f(-1.44269504088896340736f * x);
    return __builtin_amdgcn_rcpf(1.0f + t);
}
__device__ __forceinline__ float silu_f(float x) { return x * fast_sigmoid(x); }

__device__ __forceinline__ short to_bf16_bits(float f) {
    unsigned u = __builtin_bit_cast(unsigned, f);
    u += 0x7FFFu + ((u >> 16) & 1u);   // round-to-nearest-even
    return (short)(u >> 16);
}

// ---------------- Stage 1: partial[b][c] = sum over block's rows of
//   silu( silu(x_row) . W1[:,c] + b1[c] )
// MFMA 16x16x32 bf16; bias via C operand; phantom rows corrected analytically.
__global__ __launch_bounds__(1024) void k_stage1(const float* __restrict__ x,
                                                 const float* __restrict__ W1,
                                                 const float* __restrict__ b1,
                                                 float* __restrict__ partial,
                                                 int N) {
    __shared__ short xs[CHUNK * 8];     // 16 KB bf16 rows (7 padded to 8)
    __shared__ float red[NWAVE][64];    // 4 KB
    const int t = threadIdx.x;
    const int lane = t & 63;
    const int wave = t >> 6;

    // B fragments: bf[g][j] = W1pad[8*(lane>>4)+j][g*16+(lane&15)], k>=7 -> 0
    const int krow = (lane >> 4) * 8;
    const int c = lane & 15;
    short8 bf[4];
    f32x4 biasC[4];
#pragma unroll
    for (int g = 0; g < 4; ++g) {
#pragma unroll
        for (int j = 0; j < 8; ++j) {
            int k = krow + j;
            float v = (k < 7) ? W1[k * 64 + g * 16 + c] : 0.0f;
            bf[g][j] = to_bf16_bits(v);
        }
        float bb = b1[g * 16 + c];
        biasC[g] = (f32x4){bb, bb, bb, bb};
    }

    f32x4 accv[4];
#pragma unroll
    for (int g = 0; g < 4; ++g) accv[g] = (f32x4){0.0f, 0.0f, 0.0f, 0.0f};

    const int nchunk = (N + CHUNK - 1) / CHUNK;
    const short8 zero8 = {0, 0, 0, 0, 0, 0, 0, 0};
    const f32x4 onev = {1.0f, 1.0f, 1.0f, 1.0f};
    const f32x4 nlog2e = {-1.44269504088896f, -1.44269504088896f,
                          -1.44269504088896f, -1.44269504088896f};

    bool did_last = false;               // this block processed the final chunk
    for (int ch = blockIdx.x; ch < nchunk; ch += NBLK1) {
        did_last |= (ch == nchunk - 1);
        const int row = ch * CHUNK + t;
        __syncthreads();                 // prior tile reads done before overwrite
        {
            float v[7];
            if (row < N) {
#pragma unroll
                for (int k = 0; k < 7; ++k) v[k] = x[(size_t)row * 7 + k];
            } else {
#pragma unroll
                for (int k = 0; k < 7; ++k) v[k] = 0.0f;   // phantom row -> A=0
            }
            short8 p;
#pragma unroll
            for (int k = 0; k < 7; ++k) p[k] = to_bf16_bits(silu_f(v[k]));
            p[7] = 0;
            *reinterpret_cast<short8*>(&xs[t * 8]) = p;
        }
        __syncthreads();

#pragma unroll
        for (int tt = 0; tt < 4; ++tt) {
            const int tile = wave * 4 + tt;
            short8 av = *reinterpret_cast<short8*>(&xs[(tile * 16 + c) * 8]);
            av = (lane < 16) ? av : zero8;      // lanes>=16 are K-pad
#pragma unroll
            for (int g = 0; g < 4; ++g) {
                f32x4 d = __builtin_amdgcn_mfma_f32_16x16x32_bf16(av, bf[g], biasC[g], 0, 0, 0);
                // silu: 5-instr chain per element (mul, exp2, add, rcp, fma-acc)
                f32x4 targ = d * nlog2e;
                f32x4 ex;
                ex[0] = __builtin_amdgcn_exp2f(targ[0]);
                ex[1] = __builtin_amdgcn_exp2f(targ[1]);
                ex[2] = __builtin_amdgcn_exp2f(targ[2]);
                ex[3] = __builtin_amdgcn_exp2f(targ[3]);
                f32x4 den = ex + onev;
                f32x4 r;
                r[0] = __builtin_amdgcn_rcpf(den[0]);
                r[1] = __builtin_amdgcn_rcpf(den[1]);
                r[2] = __builtin_amdgcn_rcpf(den[2]);
                r[3] = __builtin_amdgcn_rcpf(den[3]);
                accv[g] = d * r + accv[g];      // packed fma
            }
        }
    }

    // collapse vector acc -> scalar per (g, col); rows split across lane>>4
    float accf[4];
#pragma unroll
    for (int g = 0; g < 4; ++g) {
        accf[g] = (accv[g][0] + accv[g][1]) + (accv[g][2] + accv[g][3]);
        accf[g] += __shfl_xor(accf[g], 16, 64);
        accf[g] += __shfl_xor(accf[g], 32, 64);
    }
    __syncthreads();
    if (lane < 16) {
#pragma unroll
        for (int g = 0; g < 4; ++g) red[wave][g * 16 + lane] = accf[g];
    }
    __syncthreads();
    if (t < 64) {
        float s = 0.0f;
#pragma unroll
        for (int wv = 0; wv < NWAVE; ++wv) s += red[wv][t];
        if (did_last) {
            // phantom rows contributed silu(b1[c]) each; remove exactly
            const int phantom = nchunk * CHUNK - N;
            s -= (float)phantom * silu_f(b1[t]);
        }
        partial[blockIdx.x * 64 + t] = s;
    }
}

// ---------------- Stage 2: redundant m-reduce (parallel over 1024 thr) +
// W2 matvec with 4-way k-split. 196 blocks x 256 outputs.
__global__ __launch_bounds__(1024) void k_out2(const float* __restrict__ partial,
                                               const float* __restrict__ W2,
                                               const float* __restrict__ b2,
                                               float* __restrict__ out,
                                               float invN) {
    __shared__ float4 red[1024];        // 16 KB
    __shared__ float ml[64];
    __shared__ float osum[4][256];      // 4 KB
    const int t = threadIdx.x;
    const int c4 = t & 15;              // float4 column group (cols 4*c4..4*c4+3)
    const int grp = t >> 4;             // 0..63
    const float4* p4 = reinterpret_cast<const float4*>(partial);

    // per-thread: 8 independent float4 loads (rows grp, grp+64, ...)
    float4 s = {0.0f, 0.0f, 0.0f, 0.0f};
#pragma unroll
    for (int r = 0; r < NBLK1 / 64; ++r) {
        float4 v = p4[(grp + r * 64) * 16 + c4];
        s.x += v.x; s.y += v.y; s.z += v.z; s.w += v.w;
    }
    red[t] = s;
    __syncthreads();
    if (t < 256) {                      // 64 partials/col -> 16
        float4 a = red[t], b = red[t + 256], cc = red[t + 512], d = red[t + 768];
        a.x += b.x + cc.x + d.x;
        a.y += b.y + cc.y + d.y;
        a.z += b.z + cc.z + d.z;
        a.w += b.w + cc.w + d.w;
        red[t] = a;                     // thread u touches only index u
    }
    __syncthreads();
    if (t < 16) {                       // 16 -> 1 per col
        float4 a = {0.0f, 0.0f, 0.0f, 0.0f};
#pragma unroll
        for (int g = 0; g < 16; ++g) {
            float4 v = red[g * 16 + t];
            a.x += v.x; a.y += v.y; a.z += v.z; a.w += v.w;
        }
        ml[4 * t + 0] = a.x * invN;
        ml[4 * t + 1] = a.y * invN;
        ml[4 * t + 2] = a.z * invN;
        ml[4 * t + 3] = a.w * invN;
    }
    __syncthreads();

    // W2 matvec: thread (s4, i) does k in [16*s4, 16*s4+16) for output j
    const int s4 = t >> 8;              // 0..3
    const int i  = t & 255;
    const int j  = blockIdx.x * 256 + i;
    float a0 = 0.0f, a1 = 0.0f, a2 = 0.0f, a3 = 0.0f;
#pragma unroll
    for (int kk = 0; kk < 4; ++kk) {
        const int k = s4 * 16 + kk * 4;
        a0 = fmaf(ml[k + 0], W2[(size_t)(k + 0) * HWOUT + j], a0);
        a1 = fmaf(ml[k + 1], W2[(size_t)(k + 1) * HWOUT + j], a1);
        a2 = fmaf(ml[k + 2], W2[(size_t)(k + 2) * HWOUT + j], a2);
        a3 = fmaf(ml[k + 3], W2[(size_t)(k + 3) * HWOUT + j], a3);
    }
    osum[s4][i] = (a0 + a1) + (a2 + a3);
    __syncthreads();
    if (t < 256) {
        const int j2 = blockIdx.x * 256 + t;
        float e = osum[0][t] + osum[1][t] + osum[2][t] + osum[3][t] + b2[j2];
        e = silu_f(e);
        out[j2] = fminf(fmaxf(e, 0.0f), 1.0f);
    }
}

extern "C" void kernel_launch(void* const* d_in, const int* in_sizes, int n_in,
                              void* d_out, int out_size, void* d_ws, size_t ws_size,
                              hipStream_t stream) {
    const float* x  = (const float*)d_in[0];
    const float* W1 = (const float*)d_in[1];
    const float* b1 = (const float*)d_in[2];
    const float* W2 = (const float*)d_in[3];
    const float* b2 = (const float*)d_in[4];
    float* out = (float*)d_out;

    const int N = in_sizes[0] / 7;
    float* partial = (float*)d_ws;   // NBLK1*64 floats = 128 KB

    k_stage1<<<NBLK1, 1024, 0, stream>>>(x, W1, b1, partial, N);
    k_out2<<<GRID2, 1024, 0, stream>>>(partial, W2, b2, out, 1.0f / (float)N);
}